// Round 2
// baseline (888.163 us; speedup 1.0000x reference)
//
#include <hip/hip_runtime.h>

#define NUM_EMB 2048
#define DIM     128
#define NVEC    65536            // 64*32*32
#define BM      64
#define BN      64
#define TSTRIDE 132              // DIM + 4 pad: 16B-aligned rows, breaks bank aliasing

// ---------------------------------------------------------------------------
// Exact replica of numpy pairwise_sum for n=128 contiguous fp32, applied to
// the element-wise product v*v (numpy materializes flat*flat first, so each
// product is individually rounded — no FMA).  Tree: 8 stride-8 accumulators
// seeded from the first 8 products, then ((r0+r1)+(r2+r3))+((r4+r5)+(r6+r7)).
// ---------------------------------------------------------------------------
__device__ __forceinline__ float np_pairwise_sumsq_128(const float* __restrict__ p)
{
    float r[8];
    #pragma unroll
    for (int j = 0; j < 8; ++j) {
        float v = p[j];
        r[j] = __fmul_rn(v, v);
    }
    #pragma unroll
    for (int i = 8; i < 128; i += 8) {
        #pragma unroll
        for (int j = 0; j < 8; ++j) {
            float v = p[i + j];
            r[j] = __fadd_rn(r[j], __fmul_rn(v, v));
        }
    }
    float s01 = __fadd_rn(r[0], r[1]);
    float s23 = __fadd_rn(r[2], r[3]);
    float s45 = __fadd_rn(r[4], r[5]);
    float s67 = __fadd_rn(r[6], r[7]);
    return __fadd_rn(__fadd_rn(s01, s23), __fadd_rn(s45, s67));
}

// ---------------------------------------------------------------------------
// Kernel 1: C_j = np-fp32 sum(e_j^2)  (numpy rounding), + zero loss accum
// ---------------------------------------------------------------------------
__global__ __launch_bounds__(256)
void enorm_kernel(const float* __restrict__ emb,
                  float* __restrict__ enorm,
                  float* __restrict__ accum)
{
    int j = blockIdx.x * 256 + threadIdx.x;
    if (j == 0) *accum = 0.0f;           // ws re-poisoned before every launch
    if (j < NUM_EMB)
        enorm[j] = np_pairwise_sumsq_128(emb + (size_t)j * DIM);
}

// ---------------------------------------------------------------------------
// Kernel 2: tiled fp32-replica distance + row argmin.
//   dist_mj = fl( fl(A_m - 2*dot_mj) + C_j )      (numpy (A-B)+C order)
//   A_m = np-pairwise sum(x^2); dot = strictly sequential-k fmaf chain
//         (bit-compatible with OpenBLAS sgemm single-accumulator k-loop).
//   argmin tie rule: first (smallest) index attaining the min.
// ---------------------------------------------------------------------------
__global__ __launch_bounds__(256)
void argmin_kernel(const float* __restrict__ z,
                   const float* __restrict__ emb,
                   const float* __restrict__ enorm,
                   int* __restrict__ out_idx)
{
    __shared__ float zs[BM * TSTRIDE];   // 33,792 B
    __shared__ float es[BN * TSTRIDE];   // 33,792 B
    __shared__ float As[BM];             // np-fp32 row norms

    const int tid = threadIdx.x;
    const int m0  = blockIdx.x * BM;

    // stage z tile: 64 rows x 128 floats, coalesced 16B loads
    #pragma unroll
    for (int i = 0; i < 8; ++i) {
        int idx = tid + i * 256;         // 0..2047
        int m   = idx >> 5;
        int dc  = idx & 31;
        float4 v = ((const float4*)(z + (size_t)(m0 + m) * DIM))[dc];
        *(float4*)&zs[m * TSTRIDE + dc * 4] = v;
    }
    __syncthreads();
    if (tid < BM)                        // numpy-exact ||x||^2 per row
        As[tid] = np_pairwise_sumsq_128(&zs[tid * TSTRIDE]);

    const int tx = tid & 15;             // code-group (4 codes)
    const int ty = tid >> 4;             // row-group  (4 rows)

    float minv[4] = {3.0e38f, 3.0e38f, 3.0e38f, 3.0e38f};
    int   mini[4] = {0, 0, 0, 0};

    for (int t = 0; t < NUM_EMB / BN; ++t) {
        __syncthreads();                 // prev-tile es readers done (also fences As at t=0)
        #pragma unroll
        for (int i = 0; i < 8; ++i) {
            int idx = tid + i * 256;
            int n   = idx >> 5;
            int dc  = idx & 31;
            float4 v = ((const float4*)(emb + (size_t)(t * BN + n) * DIM))[dc];
            *(float4*)&es[n * TSTRIDE + dc * 4] = v;
        }
        __syncthreads();

        float acc[4][4];
        #pragma unroll
        for (int r = 0; r < 4; ++r)
            #pragma unroll
            for (int c = 0; c < 4; ++c) acc[r][c] = 0.0f;

        const float* zrow = &zs[(ty * 4) * TSTRIDE];
        const float* erow = &es[(tx * 4) * TSTRIDE];

        // strictly ascending-k fused-FMA accumulation (single accumulator per
        // (r,c)) — matches BLAS sgemm rounding; do NOT reassociate.
        #pragma unroll 2
        for (int dc = 0; dc < DIM / 4; ++dc) {
            float4 zv[4], ev[4];
            #pragma unroll
            for (int r = 0; r < 4; ++r)
                zv[r] = *(const float4*)&zrow[r * TSTRIDE + dc * 4];
            #pragma unroll
            for (int c = 0; c < 4; ++c)
                ev[c] = *(const float4*)&erow[c * TSTRIDE + dc * 4];
            #pragma unroll
            for (int r = 0; r < 4; ++r)
                #pragma unroll
                for (int c = 0; c < 4; ++c) {
                    acc[r][c] = fmaf(zv[r].x, ev[c].x, acc[r][c]);
                    acc[r][c] = fmaf(zv[r].y, ev[c].y, acc[r][c]);
                    acc[r][c] = fmaf(zv[r].z, ev[c].z, acc[r][c]);
                    acc[r][c] = fmaf(zv[r].w, ev[c].w, acc[r][c]);
                }
        }

        // numpy order: t1 = fl(A - 2*dot)  [fmaf == fl(A - fl(2*dot)), 2*dot exact]
        //              s  = fl(t1 + C)
        #pragma unroll
        for (int c = 0; c < 4; ++c) {
            int   n_glob = t * BN + tx * 4 + c;
            float en     = enorm[n_glob];
            #pragma unroll
            for (int r = 0; r < 4; ++r) {
                float A  = As[ty * 4 + r];
                float t1 = fmaf(-2.0f, acc[r][c], A);
                float s  = __fadd_rn(t1, en);
                if (s < minv[r]) { minv[r] = s; mini[r] = n_glob; }   // strict <: first idx wins
            }
        }
    }

    // cross-thread reduce over the 16 tx-groups (ties -> smaller index)
    __syncthreads();
    float* rv = es;                      // [16][BM]
    int*   ri = (int*)zs;                // [16][BM]
    #pragma unroll
    for (int r = 0; r < 4; ++r) {
        int m = ty * 4 + r;
        rv[tx * BM + m] = minv[r];
        ri[tx * BM + m] = mini[r];
    }
    __syncthreads();
    if (tid < BM) {
        int   m  = tid;
        float bv = rv[m];
        int   bi = ri[m];
        #pragma unroll
        for (int j = 1; j < 16; ++j) {
            float v  = rv[j * BM + m];
            int   ix = ri[j * BM + m];
            if (v < bv || (v == bv && ix < bi)) { bv = v; bi = ix; }
        }
        out_idx[m0 + m] = bi;
    }
}

// ---------------------------------------------------------------------------
// Kernel 3: quantized_st = fl(z + fl(q - z)), indices as float,
//           accumulate sum((q - z)^2) -> one atomicAdd per block
// ---------------------------------------------------------------------------
__global__ __launch_bounds__(256)
void gather_kernel(const float* __restrict__ z,
                   const float* __restrict__ emb,
                   const int* __restrict__ idx,
                   float* __restrict__ out_q,
                   float* __restrict__ out_idx_f,
                   float* __restrict__ accum)
{
    const int tid = threadIdx.x;
    const int gid = blockIdx.x * 256 + tid;
    const int v   = gid >> 5;            // vector id
    const int c   = gid & 31;            // float4 chunk

    int j = idx[v];
    float4 q  = ((const float4*)(emb + (size_t)j * DIM))[c];
    float4 zv = ((const float4*)(z   + (size_t)v * DIM))[c];

    float4 o;                            // straight-through: z + (q - z), fp32 order
    o.x = __fadd_rn(zv.x, __fsub_rn(q.x, zv.x));
    o.y = __fadd_rn(zv.y, __fsub_rn(q.y, zv.y));
    o.z = __fadd_rn(zv.z, __fsub_rn(q.z, zv.z));
    o.w = __fadd_rn(zv.w, __fsub_rn(q.w, zv.w));
    ((float4*)out_q)[(size_t)v * 32 + c] = o;

    float dx = q.x - zv.x, dy = q.y - zv.y, dz = q.z - zv.z, dw = q.w - zv.w;
    float part = dx * dx + dy * dy + dz * dz + dw * dw;

    #pragma unroll
    for (int off = 32; off > 0; off >>= 1)
        part += __shfl_down(part, off, 64);

    __shared__ float wsum[4];
    if ((tid & 63) == 0) wsum[tid >> 6] = part;
    __syncthreads();
    if (tid == 0) atomicAdd(accum, wsum[0] + wsum[1] + wsum[2] + wsum[3]);

    if (tid < 8) {                       // this block covers 8 vectors
        int vv = blockIdx.x * 8 + tid;
        out_idx_f[vv] = (float)idx[vv];
    }
}

// ---------------------------------------------------------------------------
// Kernel 4: loss = (1 + beta) * sum / (N*D),  beta = 0.25
// ---------------------------------------------------------------------------
__global__ void finalize_kernel(const float* __restrict__ accum,
                                float* __restrict__ out_loss)
{
    *out_loss = 1.25f * (*accum) / 8388608.0f;   // N*D = 65536*128
}

// ---------------------------------------------------------------------------
extern "C" void kernel_launch(void* const* d_in, const int* in_sizes, int n_in,
                              void* d_out, int out_size, void* d_ws, size_t ws_size,
                              hipStream_t stream)
{
    const float* z   = (const float*)d_in[0];   // [65536,128]
    const float* emb = (const float*)d_in[1];   // [2048,128]
    float* out = (float*)d_out;                 // q(8388608) | idx-as-f32(65536) | loss(1)

    char*  ws    = (char*)d_ws;
    float* enorm = (float*)ws;                  // 2048 f32
    int*   idx   = (int*)(ws + 8192);           // 65536 i32
    float* accum = (float*)(ws + 8192 + 262144);

    enorm_kernel <<<NUM_EMB / 256, 256, 0, stream>>>(emb, enorm, accum);
    argmin_kernel<<<NVEC / BM,     256, 0, stream>>>(z, emb, enorm, idx);
    gather_kernel<<<NVEC / 8,      256, 0, stream>>>(z, emb, idx, out,
                                                     out + 8388608, accum);
    finalize_kernel<<<1, 1, 0, stream>>>(accum, out + 8388608 + 65536);
}

// Round 3
// 698.187 us; speedup vs baseline: 1.2721x; 1.2721x over previous
//
#include <hip/hip_runtime.h>

#define NUM_EMB 2048
#define DIM     128
#define NVEC    65536            // 64*32*32
#define BM      64
#define BN      64
#define TSTRIDE 132              // DIM + 4 pad: 16B-aligned rows; row stride ≡ 4 (mod 32) banks

// ---------------------------------------------------------------------------
// Exact replica of numpy pairwise_sum for n=128 contiguous fp32, applied to
// the element-wise product v*v (numpy materializes flat*flat first, so each
// product is individually rounded — no FMA).  Tree: 8 stride-8 accumulators
// seeded from the first 8 products, then ((r0+r1)+(r2+r3))+((r4+r5)+(r6+r7)).
// DO NOT REASSOCIATE — index correctness depends on bit-exact fp32 replica.
// ---------------------------------------------------------------------------
__device__ __forceinline__ float np_pairwise_sumsq_128(const float* __restrict__ p)
{
    float r[8];
    #pragma unroll
    for (int j = 0; j < 8; ++j) {
        float v = p[j];
        r[j] = __fmul_rn(v, v);
    }
    #pragma unroll
    for (int i = 8; i < 128; i += 8) {
        #pragma unroll
        for (int j = 0; j < 8; ++j) {
            float v = p[i + j];
            r[j] = __fadd_rn(r[j], __fmul_rn(v, v));
        }
    }
    float s01 = __fadd_rn(r[0], r[1]);
    float s23 = __fadd_rn(r[2], r[3]);
    float s45 = __fadd_rn(r[4], r[5]);
    float s67 = __fadd_rn(r[6], r[7]);
    return __fadd_rn(__fadd_rn(s01, s23), __fadd_rn(s45, s67));
}

// ---------------------------------------------------------------------------
// Kernel 1: C_j = np-fp32 sum(e_j^2), + zero loss accum
// ---------------------------------------------------------------------------
__global__ __launch_bounds__(256)
void enorm_kernel(const float* __restrict__ emb,
                  float* __restrict__ enorm,
                  float* __restrict__ accum)
{
    int j = blockIdx.x * 256 + threadIdx.x;
    if (j == 0) *accum = 0.0f;           // ws re-poisoned before every launch
    if (j < NUM_EMB)
        enorm[j] = np_pairwise_sumsq_128(emb + (size_t)j * DIM);
}

// ---------------------------------------------------------------------------
// Kernel 2: tiled fp32-replica distance + row argmin.
//   dist_mj = fl( fl(A_m - 2*dot_mj) + C_j )   (numpy (A-B)+C order)
//   dot = strictly sequential-k single-accumulator fmaf chain (BLAS-compatible)
//   Thread mapping is INTERLEAVED stride-16: thread (tx,ty) owns
//   codes {c*16+tx} and rows {r*16+ty}.  Lane-adjacent LDS reads then differ
//   by one row = 132 dwords ≡ 4 (mod 32) banks → 2-way max (free), vs the
//   blocked mapping's 4-row stride ≡ 16 (mod 32) → 8-way conflict
//   (R2: SQ_LDS_BANK_CONFLICT=2.0e8 ≈ 40% of cycles).
// ---------------------------------------------------------------------------
__global__ __launch_bounds__(256)
void argmin_kernel(const float* __restrict__ z,
                   const float* __restrict__ emb,
                   const float* __restrict__ enorm,
                   int* __restrict__ out_idx)
{
    __shared__ float zs[BM * TSTRIDE];   // 33,792 B
    __shared__ float es[BN * TSTRIDE];   // 33,792 B
    __shared__ float As[BM];             // np-fp32 row norms

    const int tid = threadIdx.x;
    const int m0  = blockIdx.x * BM;

    // stage z tile: 64 rows x 128 floats, coalesced 16B loads
    #pragma unroll
    for (int i = 0; i < 8; ++i) {
        int idx = tid + i * 256;         // 0..2047
        int m   = idx >> 5;
        int dc  = idx & 31;
        float4 v = ((const float4*)(z + (size_t)(m0 + m) * DIM))[dc];
        *(float4*)&zs[m * TSTRIDE + dc * 4] = v;
    }
    __syncthreads();
    if (tid < BM)                        // numpy-exact ||x||^2 per row
        As[tid] = np_pairwise_sumsq_128(&zs[tid * TSTRIDE]);

    const int tx = tid & 15;             // code lane: codes c*16+tx
    const int ty = tid >> 4;             // row  lane: rows  r*16+ty

    float minv[4] = {3.0e38f, 3.0e38f, 3.0e38f, 3.0e38f};
    int   mini[4] = {0, 0, 0, 0};

    const float* zrow = &zs[ty * TSTRIDE];   // + r*16*TSTRIDE
    const float* erow = &es[tx * TSTRIDE];   // + c*16*TSTRIDE

    for (int t = 0; t < NUM_EMB / BN; ++t) {
        __syncthreads();                 // prev-tile es readers done (fences As at t=0)
        #pragma unroll
        for (int i = 0; i < 8; ++i) {
            int idx = tid + i * 256;
            int n   = idx >> 5;
            int dc  = idx & 31;
            float4 v = ((const float4*)(emb + (size_t)(t * BN + n) * DIM))[dc];
            *(float4*)&es[n * TSTRIDE + dc * 4] = v;
        }
        __syncthreads();

        float acc[4][4];                 // [r][c]
        #pragma unroll
        for (int r = 0; r < 4; ++r)
            #pragma unroll
            for (int c = 0; c < 4; ++c) acc[r][c] = 0.0f;

        // strictly ascending-k fused-FMA accumulation — do NOT reassociate.
        #pragma unroll 2
        for (int dc = 0; dc < DIM / 4; ++dc) {
            float4 zv[4], ev[4];
            #pragma unroll
            for (int r = 0; r < 4; ++r)
                zv[r] = *(const float4*)&zrow[r * 16 * TSTRIDE + dc * 4];
            #pragma unroll
            for (int c = 0; c < 4; ++c)
                ev[c] = *(const float4*)&erow[c * 16 * TSTRIDE + dc * 4];
            #pragma unroll
            for (int r = 0; r < 4; ++r)
                #pragma unroll
                for (int c = 0; c < 4; ++c) {
                    acc[r][c] = fmaf(zv[r].x, ev[c].x, acc[r][c]);
                    acc[r][c] = fmaf(zv[r].y, ev[c].y, acc[r][c]);
                    acc[r][c] = fmaf(zv[r].z, ev[c].z, acc[r][c]);
                    acc[r][c] = fmaf(zv[r].w, ev[c].w, acc[r][c]);
                }
        }

        // numpy order: t1 = fl(A - 2*dot) [fmaf: 2*dot exact], s = fl(t1 + C).
        // c ascending => global code index ascending within thread; strict <
        // keeps the first index (numpy argmin tie rule).
        #pragma unroll
        for (int c = 0; c < 4; ++c) {
            int   n_glob = t * BN + c * 16 + tx;
            float en     = enorm[n_glob];
            #pragma unroll
            for (int r = 0; r < 4; ++r) {
                float A  = As[r * 16 + ty];
                float t1 = fmaf(-2.0f, acc[r][c], A);
                float s  = __fadd_rn(t1, en);
                if (s < minv[r]) { minv[r] = s; mini[r] = n_glob; }
            }
        }
    }

    // cross-thread reduce over the 16 tx-lanes (ties -> smaller index).
    // Stride-17 padding: write banks spread by tx, read stride 17 ≡ odd → ≤2-way.
    __syncthreads();
    float* rv = es;                      // [64][17]
    int*   ri = (int*)zs;                // [64][17]
    #pragma unroll
    for (int r = 0; r < 4; ++r) {
        int m = r * 16 + ty;
        rv[m * 17 + tx] = minv[r];
        ri[m * 17 + tx] = mini[r];
    }
    __syncthreads();
    if (tid < BM) {
        int   m  = tid;
        float bv = rv[m * 17];
        int   bi = ri[m * 17];
        #pragma unroll
        for (int j = 1; j < 16; ++j) {
            float v  = rv[m * 17 + j];
            int   ix = ri[m * 17 + j];
            if (v < bv || (v == bv && ix < bi)) { bv = v; bi = ix; }
        }
        out_idx[m0 + m] = bi;
    }
}

// ---------------------------------------------------------------------------
// Kernel 3: quantized_st = fl(z + fl(q - z)), indices as float,
//           accumulate sum((q - z)^2) -> one atomicAdd per block
// ---------------------------------------------------------------------------
__global__ __launch_bounds__(256)
void gather_kernel(const float* __restrict__ z,
                   const float* __restrict__ emb,
                   const int* __restrict__ idx,
                   float* __restrict__ out_q,
                   float* __restrict__ out_idx_f,
                   float* __restrict__ accum)
{
    const int tid = threadIdx.x;
    const int gid = blockIdx.x * 256 + tid;
    const int v   = gid >> 5;            // vector id
    const int c   = gid & 31;            // float4 chunk

    int j = idx[v];
    float4 q  = ((const float4*)(emb + (size_t)j * DIM))[c];
    float4 zv = ((const float4*)(z   + (size_t)v * DIM))[c];

    float4 o;                            // straight-through: z + (q - z), fp32 order
    o.x = __fadd_rn(zv.x, __fsub_rn(q.x, zv.x));
    o.y = __fadd_rn(zv.y, __fsub_rn(q.y, zv.y));
    o.z = __fadd_rn(zv.z, __fsub_rn(q.z, zv.z));
    o.w = __fadd_rn(zv.w, __fsub_rn(q.w, zv.w));
    ((float4*)out_q)[(size_t)v * 32 + c] = o;

    float dx = q.x - zv.x, dy = q.y - zv.y, dz = q.z - zv.z, dw = q.w - zv.w;
    float part = dx * dx + dy * dy + dz * dz + dw * dw;

    #pragma unroll
    for (int off = 32; off > 0; off >>= 1)
        part += __shfl_down(part, off, 64);

    __shared__ float wsum[4];
    if ((tid & 63) == 0) wsum[tid >> 6] = part;
    __syncthreads();
    if (tid == 0) atomicAdd(accum, wsum[0] + wsum[1] + wsum[2] + wsum[3]);

    if (tid < 8) {                       // this block covers 8 vectors
        int vv = blockIdx.x * 8 + tid;
        out_idx_f[vv] = (float)idx[vv];
    }
}

// ---------------------------------------------------------------------------
// Kernel 4: loss = (1 + beta) * sum / (N*D),  beta = 0.25
// ---------------------------------------------------------------------------
__global__ void finalize_kernel(const float* __restrict__ accum,
                                float* __restrict__ out_loss)
{
    *out_loss = 1.25f * (*accum) / 8388608.0f;   // N*D = 65536*128
}

// ---------------------------------------------------------------------------
extern "C" void kernel_launch(void* const* d_in, const int* in_sizes, int n_in,
                              void* d_out, int out_size, void* d_ws, size_t ws_size,
                              hipStream_t stream)
{
    const float* z   = (const float*)d_in[0];   // [65536,128]
    const float* emb = (const float*)d_in[1];   // [2048,128]
    float* out = (float*)d_out;                 // q(8388608) | idx-as-f32(65536) | loss(1)

    char*  ws    = (char*)d_ws;
    float* enorm = (float*)ws;                  // 2048 f32
    int*   idx   = (int*)(ws + 8192);           // 65536 i32
    float* accum = (float*)(ws + 8192 + 262144);

    enorm_kernel <<<NUM_EMB / 256, 256, 0, stream>>>(emb, enorm, accum);
    argmin_kernel<<<NVEC / BM,     256, 0, stream>>>(z, emb, enorm, idx);
    gather_kernel<<<NVEC / 8,      256, 0, stream>>>(z, emb, idx, out,
                                                     out + 8388608, accum);
    finalize_kernel<<<1, 1, 0, stream>>>(accum, out + 8388608 + 65536);
}